// Round 1
// 422.204 us; speedup vs baseline: 1.0108x; 1.0108x over previous
//
#include <hip/hip_runtime.h>

typedef __bf16 bf16x8 __attribute__((ext_vector_type(8)));
typedef __bf16 bf16x2 __attribute__((ext_vector_type(2)));
typedef float  f32x4  __attribute__((ext_vector_type(4)));

// sizes: E=4 B=32 CI=64 H=W=64 CO=128 OH=OW=62
// ws layout: [0, 64MiB) features bf16 NHWC [eb][y][x][i]
//            [64MiB, +576KiB) weights bf16 [e][tap][j][i]
#define FT_BYTES 67108864ull

__device__ __forceinline__ void gl2lds16(const void* g, void* l) {
    __builtin_amdgcn_global_load_lds(
        (const __attribute__((address_space(1))) void*)g,
        (__attribute__((address_space(3))) void*)l, 16, 0, 0);
}

// prepass 1: weight fp32 [e][i][j][tap] -> bf16 [e][tap][j][i]
__global__ void wt_prep(const float* __restrict__ w, __bf16* __restrict__ wt) {
    int o = blockIdx.x * 256 + threadIdx.x;           // 294912 total
    int i = o & 63, j = (o >> 6) & 127, et = o >> 13; // et 0..35
    int tap = et % 9, e = et / 9;
    wt[o] = (__bf16)w[((e * 64 + i) * 128 + j) * 9 + tap];
}

// prepass 2: features fp32 NCHW -> bf16 NHWC, one block per (e,b,y)
__global__ void ft_prep(const float* __restrict__ f, __bf16* __restrict__ ft) {
    __shared__ float s[64 * 65];                      // [i][x], +1 pad
    int eb = blockIdx.z * 32 + blockIdx.y, y = blockIdx.x;
    const float* src = f + (size_t)eb * 262144 + y * 64;
    int t = threadIdx.x;
    for (int r = 0; r < 4; ++r) {
        int f4 = r * 256 + t;                         // 1024 float4
        int i = f4 >> 4, x4 = (f4 & 15) * 4;
        float4 v = *(const float4*)(src + i * 4096 + x4);
        s[i * 65 + x4 + 0] = v.x; s[i * 65 + x4 + 1] = v.y;
        s[i * 65 + x4 + 2] = v.z; s[i * 65 + x4 + 3] = v.w;
    }
    __syncthreads();
    bf16x2* dst = (bf16x2*)(ft + (size_t)(eb * 64 + y) * 4096);
    for (int r = 0; r < 8; ++r) {
        int q = r * 256 + t;                          // 2048 bf16x2; q = x*32+ih
        int x = q >> 5, ih = q & 31;
        bf16x2 pv;
        pv.x = (__bf16)s[(2 * ih + 0) * 65 + x];
        pv.y = (__bf16)s[(2 * ih + 1) * 65 + x];
        dst[q] = pv;
    }
}

// main: per block (e,b,2-row group): out tile 128(j) x 128(p=2y*64x)
// Restructured: loop over A (3 phases). Per phase: sA holds the 3 taps
// {A*3+0..2} (48KB, single-buffered, restaged post-barrier), sB holds the
// feature rows for this A (16KB, double-buffered, prefetched during the
// previous phase's MFMAs). The Bt x-shift is applied at LDS-READ time:
// bq reads row p+Bt (clamp 127; overflow only feeds dead px>=62 cols).
// Barriers: 6/block (was 18); 96 wave-MFMAs per barrier pair (was 32).
__global__ __launch_bounds__(256, 2)
void conv_main(const __bf16* __restrict__ ft, const __bf16* __restrict__ wt,
               const float* __restrict__ bias, float* __restrict__ out) {
    __shared__ __align__(16) __bf16 sA[3 * 8192];     // [tap][j][i] 48KB
    __shared__ __align__(16) __bf16 sB[2][8192];      // [p][i] 2x16KB
    const int e = blockIdx.z, b = blockIdx.y, y0 = blockIdx.x * 2;
    const int eb = e * 32 + b;
    const int t = threadIdx.x, lane = t & 63, w = t >> 6;
    const int wm = w >> 1, wn = w & 1;                // 2x2 waves over (M,N)
    const int q = lane >> 4, rm = lane & 15;

    f32x4 acc[4][4] = {};
    const __bf16* ftb = ft + (size_t)eb * 262144;
    const __bf16* wte = wt + ((size_t)(e * 9) << 13);

    // stage 3 taps of weights for phase A; 16B chunk g at slot g^(r&7)
    auto stageA = [&](int A) {
        for (int tp = 0; tp < 3; ++tp) {
            const __bf16* wtap = wte + ((size_t)(A * 3 + tp) << 13);
            for (int cc = 0; cc < 4; ++cc) {
                int c = w * 4 + cc;
                int r = c * 8 + (lane >> 3);
                int g = (lane & 7) ^ (r & 7);
                gl2lds16(wtap + r * 64 + g * 8, sA + tp * 8192 + c * 512);
            }
        }
    };
    // stage feature rows p=(py,px) for phase A (rows y0+A, y0+A+1), unshifted
    auto stageB = [&](int A, int buf) {
        const int yA = y0 + A;
        for (int cc = 0; cc < 4; ++cc) {
            int c = w * 4 + cc;
            int p = c * 8 + (lane >> 3);
            int py = p >> 6, px = p & 63;
            int g = (lane & 7) ^ (p & 7);
            gl2lds16(ftb + (((yA + py) * 64 + px) << 6) + g * 8, sB[buf] + c * 512);
        }
    };

    stageA(0);
    stageB(0, 0);

    for (int A = 0; A < 3; ++A) {
        const int buf = A & 1;
        __syncthreads();                  // staged sA(A)+sB[buf](A) visible
        if (A < 2) stageB(A + 1, buf ^ 1);// prefetch next rows into other buf
        #pragma unroll 1
        for (int tp = 0; tp < 3; ++tp) {  // Bt = tp
            const __bf16* sAt = sA + tp * 8192;
            for (int kk = 0; kk < 64; kk += 32) {
                const int kg = kk >> 3;
                bf16x8 af[4], bq[4];
                for (int mi = 0; mi < 4; ++mi) {
                    int r = wm * 64 + mi * 16 + rm;
                    int ch = (kg + q) ^ (r & 7);
                    af[mi] = *(const bf16x8*)(sAt + r * 64 + ch * 8);
                }
                for (int ni = 0; ni < 4; ++ni) {
                    int r2 = wn * 64 + ni * 16 + rm + tp;  // x-shift at read
                    if (r2 > 127) r2 = 127;                // dead cols only
                    int ch = (kg + q) ^ (r2 & 7);
                    bq[ni] = *(const bf16x8*)(sB[buf] + r2 * 64 + ch * 8);
                }
                for (int mi = 0; mi < 4; ++mi)
                    for (int ni = 0; ni < 4; ++ni)
                        acc[mi][ni] = __builtin_amdgcn_mfma_f32_16x16x32_bf16(
                            af[mi], bq[ni], acc[mi][ni], 0, 0, 0);
            }
        }
        if (A < 2) {
            __syncthreads();              // reads of sA/sB[buf] done
            stageA(A + 1);                // restage weights (exposed ~L2 lat)
        }
    }

    // epilogue: D layout col(n=p)=lane&15, row(m=j)=(lane>>4)*4+reg
    for (int mi = 0; mi < 4; ++mi) {
        for (int ni = 0; ni < 4; ++ni) {
            int p = wn * 64 + ni * 16 + rm;
            int py = p >> 6, px = p & 63;
            if (px >= 62) continue;                   // dead padding columns
            for (int vv = 0; vv < 4; ++vv) {
                int j = wm * 64 + mi * 16 + q * 4 + vv;
                float v = acc[mi][ni][vv] + bias[e * 128 + j];
                out[(((size_t)eb * 128 + j) * 62 + (y0 + py)) * 62 + px] = v;
            }
        }
    }
}

extern "C" void kernel_launch(void* const* d_in, const int* in_sizes, int n_in,
                              void* d_out, int out_size, void* d_ws, size_t ws_size,
                              hipStream_t stream) {
    const float* f    = (const float*)d_in[0];
    const float* wgt  = (const float*)d_in[1];
    const float* bias = (const float*)d_in[2];
    float* out = (float*)d_out;
    __bf16* ftw = (__bf16*)d_ws;
    __bf16* wtw = (__bf16*)((char*)d_ws + FT_BYTES);

    ft_prep<<<dim3(64, 32, 4), 256, 0, stream>>>(f, ftw);
    wt_prep<<<dim3(1152), 256, 0, stream>>>(wgt, wtw);
    conv_main<<<dim3(31, 32, 4), 256, 0, stream>>>(ftw, wtw, bias, out);
}